// Round 14
// baseline (248.360 us; speedup 1.0000x reference)
//
#include <hip/hip_runtime.h>
#include <cstdint>

// Net_79139067396690: MC-dropout moment-propagation MLP.
//   h   = relu(0.5*x@W1^T + 0.5*sqrt((x^2)@(W1^2)^T) * eps1/sqrt(1000))
//   out =      0.5*h@W2^T + 0.5*sqrt((h^2)@(W2^2)^T) * eps2/sqrt(1000)
// Round 14 = round 13 with the swizzle fix: r13 stored chunk2 at (base^xor)+8
// but the reader expects (base+8)^xor — these differ for odd rows (bit-3 of
// the XOR). Fix: push BOTH chunk addresses through the XOR (rule #21:
// same involution on write and read). Design otherwise unchanged:
//  1) f16 GEMM inputs (cvt_pkrtz + pk-mul squares), 2) BK=64 (13 steps),
//  3) barrier-free LDS-free layer2, merged pack. All reg state NAMED (#20).

#define K_DIM 784
#define KP 832                 // K padded to 13*64
#define N_HID 256
#define N_OUT 10
#define NSTEP 13               // KP/64
#define WSQ_OFF (N_HID * KP)   // f16-unit offset of squared-W1 pack
#define W2_OFF (896 * 1024)    // byte offset of W2 pack in d_ws
#define W2SQ 4096              // f16-unit offset of squared-W2 pack
#define H_OFF (1 << 20)        // byte offset of h in d_ws

using fp16x2 = __attribute__((ext_vector_type(2))) __fp16;   // cvt_pkrtz type
using half8 = __attribute__((ext_vector_type(8))) _Float16;  // MFMA operand
using floatx4 = __attribute__((ext_vector_type(4))) float;

// ---- Threefry-2x32 (JAX-compatible) ----
__host__ __device__ inline void threefry2x32(uint32_t k0, uint32_t k1,
                                             uint32_t x0, uint32_t x1,
                                             uint32_t& o0, uint32_t& o1) {
  uint32_t ks0 = k0, ks1 = k1, ks2 = k0 ^ k1 ^ 0x1BD11BDAu;
  x0 += ks0;
  x1 += ks1;
#define TFR(r) { x0 += x1; x1 = (x1 << (r)) | (x1 >> (32 - (r))); x1 ^= x0; }
  TFR(13) TFR(15) TFR(26) TFR(6)   x0 += ks1; x1 += ks2 + 1u;
  TFR(17) TFR(29) TFR(16) TFR(24)  x0 += ks2; x1 += ks0 + 2u;
  TFR(13) TFR(15) TFR(26) TFR(6)   x0 += ks0; x1 += ks1 + 3u;
  TFR(17) TFR(29) TFR(16) TFR(24)  x0 += ks1; x1 += ks2 + 4u;
  TFR(13) TFR(15) TFR(26) TFR(6)   x0 += ks2; x1 += ks0 + 5u;
#undef TFR
  o0 = x0;
  o1 = x1;
}

// bits -> N(0,1) ~= jax.random.normal (mantissa-uniform + Giles erfinv).
__device__ __forceinline__ float bits_to_normal(uint32_t bits) {
  const float lo = -0.99999994f;  // nextafterf(-1,0)
  float u01 = __uint_as_float((bits >> 9) | 0x3F800000u) - 1.0f;
  float u = fmaxf(lo, u01 * 2.0f + lo);
  float w = -__logf((1.0f - u) * (1.0f + u));
  float p;
  if (w < 5.0f) {
    w -= 2.5f;
    p = 2.81022636e-08f;
    p = fmaf(p, w, 3.43273939e-07f);
    p = fmaf(p, w, -3.5233877e-06f);
    p = fmaf(p, w, -4.39150654e-06f);
    p = fmaf(p, w, 0.00021858087f);
    p = fmaf(p, w, -0.00125372503f);
    p = fmaf(p, w, -0.00417768164f);
    p = fmaf(p, w, 0.246640727f);
    p = fmaf(p, w, 1.50140941f);
  } else {
    w = sqrtf(w) - 3.0f;
    p = -0.000200214257f;
    p = fmaf(p, w, 0.000100950558f);
    p = fmaf(p, w, 0.00134934322f);
    p = fmaf(p, w, -0.00367342844f);
    p = fmaf(p, w, 0.00573950773f);
    p = fmaf(p, w, -0.0076224613f);
    p = fmaf(p, w, 0.00943887047f);
    p = fmaf(p, w, 1.00167406f);
    p = fmaf(p, w, 2.83297682f);
  }
  return 1.41421356f * (p * u);
}

__device__ __forceinline__ float eps_part(uint32_t ka, uint32_t kb, uint32_t i) {
  uint32_t o0, o1;
  threefry2x32(ka, kb, 0u, i, o0, o1);
  return bits_to_normal(o0 ^ o1);
}

__device__ __forceinline__ int h2i(fp16x2 h) {
  union { fp16x2 h; int i; } u;
  u.h = h;
  return u.i;
}

// ---- pack W1 (blocks 0..255) and W2 (block 256) -> f16 {w, w^2} ----
__global__ __launch_bounds__(256) void pack_w(const float* __restrict__ W1,
                                              const float* __restrict__ W2,
                                              _Float16* __restrict__ bp,
                                              _Float16* __restrict__ w2p) {
  const int b = blockIdx.x;
  if (b < 256) {
    for (int k = threadIdx.x; k < KP; k += 256) {
      float w = (k < K_DIM) ? W1[b * K_DIM + k] : 0.0f;
      bp[b * KP + k] = (_Float16)w;
      bp[WSQ_OFF + b * KP + k] = (_Float16)(w * w);
    }
  } else {
#pragma unroll
    for (int i = 0; i < 16; ++i) {
      int g = threadIdx.x + i * 256;  // 4096 = 16*256
      int col = g >> 8, k = g & 255;
      float w = (col < N_OUT) ? W2[col * N_HID + k] : 0.0f;
      w2p[g] = (_Float16)w;
      w2p[W2SQ + g] = (_Float16)(w * w);
    }
  }
}

// ---- GEMM1 + eps1 + relu -> h (f16, global) ----
// Block: 256 thr = 4 waves; 64 rows x 128 cols; wave = 64x32; BK=64.
__global__ __launch_bounds__(256, 4) void gemm1(
    const float* __restrict__ x, const _Float16* __restrict__ bp,
    _Float16* __restrict__ hws, uint32_t k1a, uint32_t k1b) {
  __shared__ _Float16 sA[2][2][64 * 64];  // 32 KB [dbuf][x, x^2][swizzled]

  const int tid = threadIdx.x;
  const int lane = tid & 63;
  const int l15 = lane & 15;
  const int lhal = lane >> 4;      // 0..3
  const int wn = tid >> 6;         // wave id 0..3 -> 32-col strip
  const int bid = blockIdx.x;
  const int gr0 = (bid >> 1) * 64;        // row origin
  const int bc0 = (bid & 1) * 128;        // col origin

  // staging: thread -> (row 0..63, 16-wide k chunk); BOTH 8-chunk addresses
  // go through the XOR (rule #21 — the r13 bug was (base^xor)+8).
  const int srow = tid >> 2;
  const int skq = (tid & 3) * 16;
  const float* xptr = x + (size_t)(gr0 + srow) * K_DIM + skq;
  const int sxor = (srow & 7) << 3;
  const int sidxA = (srow * 64 + skq) ^ sxor;      // f16 units
  const int sidxB = (srow * 64 + skq + 8) ^ sxor;  // f16 units

  // B offsets (f16 units) for this wave's two 16-col fragments
  const uint32_t boff0 = (uint32_t)(bc0 + wn * 32 + l15) * KP + (uint32_t)lhal * 8;
  const uint32_t boff1 = boff0 + 16u * KP;

  // A fragment LDS indices, NAMED (i = frag row-tile, kc = 32-k half)
#define AIDX(i, kc) ((((i * 16 + l15) * 64) + (kc) * 32 + lhal * 8) ^ ((l15 & 7) << 3))
  const int aidx00 = AIDX(0, 0), aidx01 = AIDX(0, 1);
  const int aidx10 = AIDX(1, 0), aidx11 = AIDX(1, 1);
  const int aidx20 = AIDX(2, 0), aidx21 = AIDX(2, 1);
  const int aidx30 = AIDX(3, 0), aidx31 = AIDX(3, 1);
#undef AIDX

  // NAMED accumulators: am{i}{j}, av{i}{j}, i=0..3, j=0..1
#define DECL_ACC(i) \
  floatx4 am##i##0 = {0.f, 0.f, 0.f, 0.f}, am##i##1 = {0.f, 0.f, 0.f, 0.f}; \
  floatx4 av##i##0 = {0.f, 0.f, 0.f, 0.f}, av##i##1 = {0.f, 0.f, 0.f, 0.f};
  DECL_ACC(0) DECL_ACC(1) DECL_ACC(2) DECL_ACC(3)
#undef DECL_ACC

  float4 q0, q1, q2, q3;
  auto loadX = [&](int kk) {
    if (kk + skq < K_DIM) {  // 16-chunk fully valid or fully OOB (784 = 49*16)
      q0 = *reinterpret_cast<const float4*>(xptr + kk);
      q1 = *reinterpret_cast<const float4*>(xptr + kk + 4);
      q2 = *reinterpret_cast<const float4*>(xptr + kk + 8);
      q3 = *reinterpret_cast<const float4*>(xptr + kk + 12);
    } else {
      q0 = q1 = q2 = q3 = make_float4(0.f, 0.f, 0.f, 0.f);
    }
  };
  auto writeA = [&](int buf) {
    const fp16x2 a0 = __builtin_amdgcn_cvt_pkrtz(q0.x, q0.y);
    const fp16x2 a1 = __builtin_amdgcn_cvt_pkrtz(q0.z, q0.w);
    const fp16x2 a2 = __builtin_amdgcn_cvt_pkrtz(q1.x, q1.y);
    const fp16x2 a3 = __builtin_amdgcn_cvt_pkrtz(q1.z, q1.w);
    const fp16x2 a4 = __builtin_amdgcn_cvt_pkrtz(q2.x, q2.y);
    const fp16x2 a5 = __builtin_amdgcn_cvt_pkrtz(q2.z, q2.w);
    const fp16x2 a6 = __builtin_amdgcn_cvt_pkrtz(q3.x, q3.y);
    const fp16x2 a7 = __builtin_amdgcn_cvt_pkrtz(q3.z, q3.w);
    const fp16x2 s0 = a0 * a0, s1 = a1 * a1, s2 = a2 * a2, s3 = a3 * a3;
    const fp16x2 s4 = a4 * a4, s5 = a5 * a5, s6 = a6 * a6, s7 = a7 * a7;
    int4 wa0, wa1, wb0, wb1;
    wa0.x = h2i(a0); wa0.y = h2i(a1); wa0.z = h2i(a2); wa0.w = h2i(a3);
    wa1.x = h2i(a4); wa1.y = h2i(a5); wa1.z = h2i(a6); wa1.w = h2i(a7);
    wb0.x = h2i(s0); wb0.y = h2i(s1); wb0.z = h2i(s2); wb0.w = h2i(s3);
    wb1.x = h2i(s4); wb1.y = h2i(s5); wb1.z = h2i(s6); wb1.w = h2i(s7);
    *reinterpret_cast<int4*>(&sA[buf][0][sidxA]) = wa0;
    *reinterpret_cast<int4*>(&sA[buf][0][sidxB]) = wa1;
    *reinterpret_cast<int4*>(&sA[buf][1][sidxA]) = wb0;
    *reinterpret_cast<int4*>(&sA[buf][1][sidxB]) = wb1;
  };

  // prologue: stage step 0
  loadX(0);
  writeA(0);
  __syncthreads();

  for (int s = 0; s < NSTEP; ++s) {
    const int cur = s & 1;
    const bool have = (s + 1 < NSTEP);
    const int kk = s * 64;

    if (have) loadX(kk + 64);  // next-tile loads in flight during MFMAs

    const _Float16* sc0 = &sA[cur][0][0];
    const _Float16* sc1 = &sA[cur][1][0];

#define KC_BLOCK(kc) { \
    const _Float16* bpk = bp + kk + (kc) * 32; \
    const half8 bm0 = *reinterpret_cast<const half8*>(&bpk[boff0]); \
    const half8 bm1 = *reinterpret_cast<const half8*>(&bpk[boff1]); \
    const half8 bv0 = *reinterpret_cast<const half8*>(&bpk[WSQ_OFF + boff0]); \
    const half8 bv1 = *reinterpret_cast<const half8*>(&bpk[WSQ_OFF + boff1]); \
    { \
      const half8 af0 = *reinterpret_cast<const half8*>(&sc0[aidx0##kc]); \
      const half8 ag0 = *reinterpret_cast<const half8*>(&sc1[aidx0##kc]); \
      const half8 af1 = *reinterpret_cast<const half8*>(&sc0[aidx1##kc]); \
      const half8 ag1 = *reinterpret_cast<const half8*>(&sc1[aidx1##kc]); \
      am00 = __builtin_amdgcn_mfma_f32_16x16x32_f16(af0, bm0, am00, 0, 0, 0); \
      av00 = __builtin_amdgcn_mfma_f32_16x16x32_f16(ag0, bv0, av00, 0, 0, 0); \
      am01 = __builtin_amdgcn_mfma_f32_16x16x32_f16(af0, bm1, am01, 0, 0, 0); \
      av01 = __builtin_amdgcn_mfma_f32_16x16x32_f16(ag0, bv1, av01, 0, 0, 0); \
      am10 = __builtin_amdgcn_mfma_f32_16x16x32_f16(af1, bm0, am10, 0, 0, 0); \
      av10 = __builtin_amdgcn_mfma_f32_16x16x32_f16(ag1, bv0, av10, 0, 0, 0); \
      am11 = __builtin_amdgcn_mfma_f32_16x16x32_f16(af1, bm1, am11, 0, 0, 0); \
      av11 = __builtin_amdgcn_mfma_f32_16x16x32_f16(ag1, bv1, av11, 0, 0, 0); \
    } \
    { \
      const half8 af2 = *reinterpret_cast<const half8*>(&sc0[aidx2##kc]); \
      const half8 ag2 = *reinterpret_cast<const half8*>(&sc1[aidx2##kc]); \
      const half8 af3 = *reinterpret_cast<const half8*>(&sc0[aidx3##kc]); \
      const half8 ag3 = *reinterpret_cast<const half8*>(&sc1[aidx3##kc]); \
      am20 = __builtin_amdgcn_mfma_f32_16x16x32_f16(af2, bm0, am20, 0, 0, 0); \
      av20 = __builtin_amdgcn_mfma_f32_16x16x32_f16(ag2, bv0, av20, 0, 0, 0); \
      am21 = __builtin_amdgcn_mfma_f32_16x16x32_f16(af2, bm1, am21, 0, 0, 0); \
      av21 = __builtin_amdgcn_mfma_f32_16x16x32_f16(ag2, bv1, av21, 0, 0, 0); \
      am30 = __builtin_amdgcn_mfma_f32_16x16x32_f16(af3, bm0, am30, 0, 0, 0); \
      av30 = __builtin_amdgcn_mfma_f32_16x16x32_f16(ag3, bv0, av30, 0, 0, 0); \
      am31 = __builtin_amdgcn_mfma_f32_16x16x32_f16(af3, bm1, am31, 0, 0, 0); \
      av31 = __builtin_amdgcn_mfma_f32_16x16x32_f16(ag3, bv1, av31, 0, 0, 0); \
    } }
    KC_BLOCK(0)
    KC_BLOCK(1)
#undef KC_BLOCK

    if (have) writeA(cur ^ 1);  // write-late: loads drained here, not earlier
    __syncthreads();
  }

  // epilogue: eps1 + relu -> h (f16) in global ws
  const float INV = 0.031622776601683794f;  // 1/sqrt(1000)
#define EPIG(AM, AV, G, I, J) do { \
    const int rl_ = I * 16 + lhal * 4 + (G); \
    const int c_ = bc0 + wn * 32 + J * 16 + l15; \
    float mean_ = 0.5f * (AM)[G]; \
    float sd_ = 0.5f * sqrtf((AV)[G]); \
    uint32_t idx_ = (uint32_t)(gr0 + rl_) * 256u + (uint32_t)c_; \
    float eps_ = eps_part(k1a, k1b, idx_); \
    float h_ = fmaxf(mean_ + sd_ * (eps_ * INV), 0.0f); \
    hws[(size_t)(gr0 + rl_) * 256 + c_] = (_Float16)h_; \
  } while (0)
#define EPI(i, j) do { \
    EPIG(am##i##j, av##i##j, 0, i, j); \
    EPIG(am##i##j, av##i##j, 1, i, j); \
    EPIG(am##i##j, av##i##j, 2, i, j); \
    EPIG(am##i##j, av##i##j, 3, i, j); \
  } while (0)
  EPI(0, 0); EPI(0, 1); EPI(1, 0); EPI(1, 1);
  EPI(2, 0); EPI(2, 1); EPI(3, 0); EPI(3, 1);
#undef EPI
#undef EPIG
}

// ---- layer 2: barrier-free, LDS-free. Block: 256 thr = 4 waves x 32 rows. ----
__global__ __launch_bounds__(256, 8) void layer2(
    const _Float16* __restrict__ hws, const _Float16* __restrict__ w2p,
    float* __restrict__ out, uint32_t k2a, uint32_t k2b) {
  const int tid = threadIdx.x;
  const int lane = tid & 63;
  const int l15 = lane & 15;
  const int lhal = lane >> 4;  // 0..3
  const int wv = tid >> 6;     // wave 0..3 -> rows wv*32..wv*32+31
  const int gr0 = blockIdx.x * 128;

  // A row pointers (wave-exclusive rows -> no sharing needed)
  const _Float16* h0 = hws + (size_t)(gr0 + wv * 32 + l15) * 256 + lhal * 8;
  const _Float16* h1 = h0 + 16 * 256;
  const uint32_t boff = (uint32_t)l15 * 256 + (uint32_t)lhal * 8;

  floatx4 am0 = {0.f, 0.f, 0.f, 0.f}, am1 = {0.f, 0.f, 0.f, 0.f};
  floatx4 av0 = {0.f, 0.f, 0.f, 0.f}, av1 = {0.f, 0.f, 0.f, 0.f};

#define L2S(S) do { \
    const half8 af0 = *reinterpret_cast<const half8*>(h0 + (S) * 32); \
    const half8 af1 = *reinterpret_cast<const half8*>(h1 + (S) * 32); \
    const half8 ag0 = af0 * af0; \
    const half8 ag1 = af1 * af1; \
    const half8 bm = *reinterpret_cast<const half8*>(&w2p[boff + (S) * 32]); \
    const half8 bv = *reinterpret_cast<const half8*>(&w2p[W2SQ + boff + (S) * 32]); \
    am0 = __builtin_amdgcn_mfma_f32_16x16x32_f16(af0, bm, am0, 0, 0, 0); \
    av0 = __builtin_amdgcn_mfma_f32_16x16x32_f16(ag0, bv, av0, 0, 0, 0); \
    am1 = __builtin_amdgcn_mfma_f32_16x16x32_f16(af1, bm, am1, 0, 0, 0); \
    av1 = __builtin_amdgcn_mfma_f32_16x16x32_f16(ag1, bv, av1, 0, 0, 0); \
  } while (0)
  L2S(0); L2S(1); L2S(2); L2S(3); L2S(4); L2S(5); L2S(6); L2S(7);
#undef L2S

  // epilogue: C/D layout col=l15, row=(lane>>4)*4+g; only cols 0..9 exist
  const float INV = 0.031622776601683794f;
  if (l15 < N_OUT) {
#define L2E(I, G) do { \
    const int row_ = gr0 + wv * 32 + I * 16 + lhal * 4 + (G); \
    float mean_ = 0.5f * am##I[G]; \
    float sd_ = 0.5f * sqrtf(av##I[G]); \
    float eps_ = eps_part(k2a, k2b, (uint32_t)row_ * 10u + (uint32_t)l15); \
    out[(size_t)row_ * 10 + l15] = mean_ + sd_ * (eps_ * INV); \
  } while (0)
    L2E(0, 0); L2E(0, 1); L2E(0, 2); L2E(0, 3);
    L2E(1, 0); L2E(1, 1); L2E(1, 2); L2E(1, 3);
#undef L2E
  }
}

extern "C" void kernel_launch(void* const* d_in, const int* in_sizes, int n_in,
                              void* d_out, int out_size, void* d_ws, size_t ws_size,
                              hipStream_t stream) {
  const float* x = (const float*)d_in[0];
  const float* W1 = (const float*)d_in[1];
  const float* W2 = (const float*)d_in[2];
  float* outp = (float*)d_out;
  _Float16* bp = (_Float16*)d_ws;                        // 851,968 B
  _Float16* w2p = (_Float16*)((char*)d_ws + W2_OFF);     // 16 KB
  _Float16* hws = (_Float16*)((char*)d_ws + H_OFF);      // 33.5 MB

  // k1, k2 = jax.random.split(jax.random.key(42)), partitionable threefry
  uint32_t k1a, k1b, k2a, k2b;
  threefry2x32(0u, 42u, 0u, 0u, k1a, k1b);
  threefry2x32(0u, 42u, 0u, 1u, k2a, k2b);

  pack_w<<<257, 256, 0, stream>>>(W1, W2, bp, w2p);
  gemm1<<<2048, 256, 0, stream>>>(x, bp, hws, k1a, k1b);
  layer2<<<512, 256, 0, stream>>>(hws, w2p, outp, k2a, k2b);
}

// Round 16
// 207.464 us; speedup vs baseline: 1.1971x; 1.1971x over previous
//
#include <hip/hip_runtime.h>
#include <cstdint>

// Net_79139067396690: MC-dropout moment-propagation MLP.
//   h   = relu(0.5*x@W1^T + 0.5*sqrt((x^2)@(W1^2)^T) * eps1/sqrt(1000))
//   out =      0.5*h@W2^T + 0.5*sqrt((h^2)@(W2^2)^T) * eps2/sqrt(1000)
// Round 16 = round 15 with the compile fix (cvt_bf16 had a stray
// __hip_bfloat16_raw union member; the function computes RNE bits directly).
// Design: r9 base (158us, spill-free) + eps1 RNG hoisted to high-occupancy
// rng1 kernel (8 waves/SIMD, pure VALU), f16 eps in gemm1's per-thread
// layout, int4-coalesced; gemm1<1> reads 4x16B. ws_size guard -> gemm1<0>.
// All register state NAMED (rule #20). Swizzle both-sides (rule #21).

#define K_DIM 784
#define KP 800                 // K padded to multiple of 32 in the W1 pack
#define N_HID 256
#define N_OUT 10
#define NSTEP 25               // KP/32
#define WSQ_OFF (N_HID * KP)   // u16 offset of squared-W1 pack
#define W2_OFF (832 * 1024)    // byte offset of W2 pack in d_ws
#define W2SQ 4096              // u16 offset of squared-W2 pack
#define EPS_OFF 1048576        // byte offset of eps1 (33.5 MB)
#define H_BIG 34603008         // byte offset of h when eps present
#define H_SMALL 1048576        // byte offset of h in fallback layout
#define BM2 128                // layer2 rows per block

using short8 = __attribute__((ext_vector_type(8))) short;
using half8 = __attribute__((ext_vector_type(8))) _Float16;
using fp16x2 = __attribute__((ext_vector_type(2))) __fp16;
using floatx4 = __attribute__((ext_vector_type(4))) float;
typedef uint16_t u16;

// ---- Threefry-2x32 (JAX-compatible) ----
__host__ __device__ inline void threefry2x32(uint32_t k0, uint32_t k1,
                                             uint32_t x0, uint32_t x1,
                                             uint32_t& o0, uint32_t& o1) {
  uint32_t ks0 = k0, ks1 = k1, ks2 = k0 ^ k1 ^ 0x1BD11BDAu;
  x0 += ks0;
  x1 += ks1;
#define TFR(r) { x0 += x1; x1 = (x1 << (r)) | (x1 >> (32 - (r))); x1 ^= x0; }
  TFR(13) TFR(15) TFR(26) TFR(6)   x0 += ks1; x1 += ks2 + 1u;
  TFR(17) TFR(29) TFR(16) TFR(24)  x0 += ks2; x1 += ks0 + 2u;
  TFR(13) TFR(15) TFR(26) TFR(6)   x0 += ks0; x1 += ks1 + 3u;
  TFR(17) TFR(29) TFR(16) TFR(24)  x0 += ks1; x1 += ks2 + 4u;
  TFR(13) TFR(15) TFR(26) TFR(6)   x0 += ks2; x1 += ks0 + 5u;
#undef TFR
  o0 = x0;
  o1 = x1;
}

// bits -> N(0,1) ~= jax.random.normal (mantissa-uniform + Giles erfinv).
__device__ __forceinline__ float bits_to_normal(uint32_t bits) {
  const float lo = -0.99999994f;  // nextafterf(-1,0)
  float u01 = __uint_as_float((bits >> 9) | 0x3F800000u) - 1.0f;
  float u = fmaxf(lo, u01 * 2.0f + lo);
  float w = -__logf((1.0f - u) * (1.0f + u));
  float p;
  if (w < 5.0f) {
    w -= 2.5f;
    p = 2.81022636e-08f;
    p = fmaf(p, w, 3.43273939e-07f);
    p = fmaf(p, w, -3.5233877e-06f);
    p = fmaf(p, w, -4.39150654e-06f);
    p = fmaf(p, w, 0.00021858087f);
    p = fmaf(p, w, -0.00125372503f);
    p = fmaf(p, w, -0.00417768164f);
    p = fmaf(p, w, 0.246640727f);
    p = fmaf(p, w, 1.50140941f);
  } else {
    w = sqrtf(w) - 3.0f;
    p = -0.000200214257f;
    p = fmaf(p, w, 0.000100950558f);
    p = fmaf(p, w, 0.00134934322f);
    p = fmaf(p, w, -0.00367342844f);
    p = fmaf(p, w, 0.00573950773f);
    p = fmaf(p, w, -0.0076224613f);
    p = fmaf(p, w, 0.00943887047f);
    p = fmaf(p, w, 1.00167406f);
    p = fmaf(p, w, 2.83297682f);
  }
  return 1.41421356f * (p * u);
}

__device__ __forceinline__ float eps_part(uint32_t ka, uint32_t kb, uint32_t i) {
  uint32_t o0, o1;
  threefry2x32(ka, kb, 0u, i, o0, o1);
  return bits_to_normal(o0 ^ o1);
}

// f32 -> bf16 bits, round-to-nearest-even
__device__ __forceinline__ u16 cvt_bf16(float f) {
  uint32_t x = __float_as_uint(f);
  return (u16)((x + 0x7FFFu + ((x >> 16) & 1u)) >> 16);
}

__device__ __forceinline__ float bf2f(u16 b) {
  return __uint_as_float((uint32_t)b << 16);
}

__device__ __forceinline__ int h2i(fp16x2 h) {
  union { fp16x2 h; int i; } u;
  u.h = h;
  return u.i;
}

// ---- pre-pack W1 -> bf16 {w, w^2}, K padded to 800 with zeros ----
__global__ __launch_bounds__(256) void pack_w1(const float* __restrict__ W1,
                                               u16* __restrict__ bp) {
  const int col = blockIdx.x;  // 0..255
  for (int k = threadIdx.x; k < KP; k += 256) {
    float w = (k < K_DIM) ? W1[col * K_DIM + k] : 0.0f;
    bp[col * KP + k] = cvt_bf16(w);
    bp[WSQ_OFF + col * KP + k] = cvt_bf16(w * w);
  }
}

// ---- pre-pack W2 -> bf16 {w, w^2}, cols padded 10->16 with zeros ----
__global__ __launch_bounds__(256) void pack_w2(const float* __restrict__ W2,
                                               u16* __restrict__ w2p) {
#pragma unroll
  for (int i = 0; i < 16; ++i) {
    int g = threadIdx.x + i * 256;  // 4096 = 16*256
    int col = g >> 8, k = g & 255;
    float w = (col < N_OUT) ? W2[col * N_HID + k] : 0.0f;
    w2p[g] = cvt_bf16(w);
    w2p[W2SQ + g] = cvt_bf16(w * w);
  }
}

// ---- rng1: all 16.8M eps1 draws, f16, in gemm1's per-thread layout ----
// Geometry mirrors gemm1 (2048 blocks x 256 thr). Draw d of thread:
// i=d>>3, j=(d>>2)&1, g=d&3; idx=(gr0+i*16+lhal*4+g)*256+(bc0+wn*32+j*16+l15).
// Store (int4 units): ei4[bid*1024 + i*256 + tid] -> coalesced 16B/lane.
__global__ __launch_bounds__(256, 8) void rng1(int4* __restrict__ ei4,
                                               uint32_t k1a, uint32_t k1b) {
  const int tid = threadIdx.x;
  const int lane = tid & 63;
  const int l15 = lane & 15;
  const int lhal = lane >> 4;
  const int wn = tid >> 6;
  const int bid = blockIdx.x;
  const int gr0 = (bid >> 1) * 64;
  const int bc0 = (bid & 1) * 128;

#define EIDX(D) ((uint32_t)(gr0 + ((D) >> 3) * 16 + lhal * 4 + ((D) & 3)) * 256u \
                 + (uint32_t)(bc0 + wn * 32 + (((D) >> 2) & 1) * 16 + l15))
#define PKE(P, D) const fp16x2 P = __builtin_amdgcn_cvt_pkrtz( \
    eps_part(k1a, k1b, EIDX(D)), eps_part(k1a, k1b, EIDX((D) + 1)));
  PKE(p0, 0)  PKE(p1, 2)  PKE(p2, 4)  PKE(p3, 6)
  PKE(p4, 8)  PKE(p5, 10) PKE(p6, 12) PKE(p7, 14)
  PKE(p8, 16) PKE(p9, 18) PKE(pa, 20) PKE(pb, 22)
  PKE(pc, 24) PKE(pd, 26) PKE(pe, 28) PKE(pf, 30)
#undef PKE
#undef EIDX
  int4 w0, w1, w2, w3;
  w0.x = h2i(p0); w0.y = h2i(p1); w0.z = h2i(p2); w0.w = h2i(p3);
  w1.x = h2i(p4); w1.y = h2i(p5); w1.z = h2i(p6); w1.w = h2i(p7);
  w2.x = h2i(p8); w2.y = h2i(p9); w2.z = h2i(pa); w2.w = h2i(pb);
  w3.x = h2i(pc); w3.y = h2i(pd); w3.z = h2i(pe); w3.w = h2i(pf);
  int4* dst = ei4 + (size_t)bid * 1024 + tid;
  dst[0] = w0;
  dst[256] = w1;
  dst[512] = w2;
  dst[768] = w3;
}

// ---- GEMM1 + eps1 + relu -> h (bf16, global). UE=1: eps from rng1 ws. ----
// Block: 256 thr = 4 waves; 64 rows x 128 cols; wave = 64 x 32. (r9 exact)
template <int UE>
__global__ __launch_bounds__(256, 4) void gemm1(
    const float* __restrict__ x, const u16* __restrict__ bp,
    u16* __restrict__ hws, const int4* __restrict__ ei4,
    uint32_t k1a, uint32_t k1b) {
  __shared__ u16 sA[2][2][64 * 32];  // [dbuf][x, x^2][swizzled row*32+k] 16KB

  const int tid = threadIdx.x;
  const int lane = tid & 63;
  const int l15 = lane & 15;
  const int lhal = lane >> 4;      // 0..3
  const int wn = tid >> 6;         // wave id 0..3 -> 32-col strip
  const int bid = blockIdx.x;
  const int gr0 = (bid >> 1) * 64;        // row origin
  const int bc0 = (bid & 1) * 128;        // col origin

  // staging: thread -> (row 0..63, 8-wide k chunk)
  const int srow = tid >> 2;
  const int skq = (tid & 3) * 8;
  const float* xptr = x + (size_t)(gr0 + srow) * K_DIM + skq;
  const int sidx = (srow * 32 + skq) ^ ((srow & 7) << 3);

  // B offsets (u16 units) for this wave's two 16-col fragments
  const uint32_t boff0 = (uint32_t)(bc0 + wn * 32 + 0 * 16 + l15) * KP + (uint32_t)lhal * 8;
  const uint32_t boff1 = (uint32_t)(bc0 + wn * 32 + 1 * 16 + l15) * KP + (uint32_t)lhal * 8;

  // A fragment LDS indices (rows i*16 + l15, k-group lhal*8), NAMED
#define AIDX(i) ((((i * 16 + l15) * 32 + lhal * 8)) ^ (((i * 16 + l15) & 7) << 3))
  const int aidx0 = AIDX(0);
  const int aidx1 = AIDX(1);
  const int aidx2 = AIDX(2);
  const int aidx3 = AIDX(3);
#undef AIDX

  // NAMED accumulators: am{i}{j}, av{i}{j}, i=0..3, j=0..1
#define DECL_ACC(i) \
  floatx4 am##i##0 = {0.f, 0.f, 0.f, 0.f}, am##i##1 = {0.f, 0.f, 0.f, 0.f}; \
  floatx4 av##i##0 = {0.f, 0.f, 0.f, 0.f}, av##i##1 = {0.f, 0.f, 0.f, 0.f};
  DECL_ACC(0) DECL_ACC(1) DECL_ACC(2) DECL_ACC(3)
#undef DECL_ACC

  // NAMED ping/pong B register sets (16 VGPR each)
  short8 bm0P, bm1P, bv0P, bv1P;
  short8 bm0Q, bm1Q, bv0Q, bv1Q;
#define LOADB(S, KK) do { \
    const u16* bpk_ = bp + (KK); \
    bm0##S = *reinterpret_cast<const short8*>(&bpk_[boff0]); \
    bm1##S = *reinterpret_cast<const short8*>(&bpk_[boff1]); \
    bv0##S = *reinterpret_cast<const short8*>(&bpk_[WSQ_OFF + boff0]); \
    bv1##S = *reinterpret_cast<const short8*>(&bpk_[WSQ_OFF + boff1]); \
  } while (0)

  float4 q0, q1;
  auto loadX = [&](int kk) {
    if (kk + skq + 8 <= K_DIM) {  // K tail (784 = 24*32+16): zero-fill OOB
      q0 = *reinterpret_cast<const float4*>(xptr + kk);
      q1 = *reinterpret_cast<const float4*>(xptr + kk + 4);
    } else {
      q0 = make_float4(0.f, 0.f, 0.f, 0.f);
      q1 = make_float4(0.f, 0.f, 0.f, 0.f);
    }
  };
  auto writeA = [&](int buf) {
    short8 va, v2;
    va[0] = (short)cvt_bf16(q0.x); v2[0] = (short)cvt_bf16(q0.x * q0.x);
    va[1] = (short)cvt_bf16(q0.y); v2[1] = (short)cvt_bf16(q0.y * q0.y);
    va[2] = (short)cvt_bf16(q0.z); v2[2] = (short)cvt_bf16(q0.z * q0.z);
    va[3] = (short)cvt_bf16(q0.w); v2[3] = (short)cvt_bf16(q0.w * q0.w);
    va[4] = (short)cvt_bf16(q1.x); v2[4] = (short)cvt_bf16(q1.x * q1.x);
    va[5] = (short)cvt_bf16(q1.y); v2[5] = (short)cvt_bf16(q1.y * q1.y);
    va[6] = (short)cvt_bf16(q1.z); v2[6] = (short)cvt_bf16(q1.z * q1.z);
    va[7] = (short)cvt_bf16(q1.w); v2[7] = (short)cvt_bf16(q1.w * q1.w);
    *reinterpret_cast<short8*>(&sA[buf][0][sidx]) = va;
    *reinterpret_cast<short8*>(&sA[buf][1][sidx]) = v2;
  };

  // One K-step: uses B set CUR (already resident), prefetches set NXT.
#define KSTEP(S_, CUR, NXT, LAST) do { \
    const int kk_ = (S_) * 32; \
    if (!(LAST)) { loadX(kk_ + 32); LOADB(NXT, kk_ + 32); } \
    const u16* sc0_ = &sA[(S_) & 1][0][0]; \
    const u16* sc1_ = &sA[(S_) & 1][1][0]; \
    { \
      const short8 af0_ = *reinterpret_cast<const short8*>(&sc0_[aidx0]); \
      const short8 ag0_ = *reinterpret_cast<const short8*>(&sc1_[aidx0]); \
      const short8 af1_ = *reinterpret_cast<const short8*>(&sc0_[aidx1]); \
      const short8 ag1_ = *reinterpret_cast<const short8*>(&sc1_[aidx1]); \
      const short8 af2_ = *reinterpret_cast<const short8*>(&sc0_[aidx2]); \
      const short8 ag2_ = *reinterpret_cast<const short8*>(&sc1_[aidx2]); \
      const short8 af3_ = *reinterpret_cast<const short8*>(&sc0_[aidx3]); \
      const short8 ag3_ = *reinterpret_cast<const short8*>(&sc1_[aidx3]); \
      am00 = __builtin_amdgcn_mfma_f32_16x16x32_bf16(af0_, bm0##CUR, am00, 0, 0, 0); \
      av00 = __builtin_amdgcn_mfma_f32_16x16x32_bf16(ag0_, bv0##CUR, av00, 0, 0, 0); \
      am01 = __builtin_amdgcn_mfma_f32_16x16x32_bf16(af0_, bm1##CUR, am01, 0, 0, 0); \
      av01 = __builtin_amdgcn_mfma_f32_16x16x32_bf16(ag0_, bv1##CUR, av01, 0, 0, 0); \
      am10 = __builtin_amdgcn_mfma_f32_16x16x32_bf16(af1_, bm0##CUR, am10, 0, 0, 0); \
      av10 = __builtin_amdgcn_mfma_f32_16x16x32_bf16(ag1_, bv0##CUR, av10, 0, 0, 0); \
      am11 = __builtin_amdgcn_mfma_f32_16x16x32_bf16(af1_, bm1##CUR, am11, 0, 0, 0); \
      av11 = __builtin_amdgcn_mfma_f32_16x16x32_bf16(ag1_, bv1##CUR, av11, 0, 0, 0); \
      am20 = __builtin_amdgcn_mfma_f32_16x16x32_bf16(af2_, bm0##CUR, am20, 0, 0, 0); \
      av20 = __builtin_amdgcn_mfma_f32_16x16x32_bf16(ag2_, bv0##CUR, av20, 0, 0, 0); \
      am21 = __builtin_amdgcn_mfma_f32_16x16x32_bf16(af2_, bm1##CUR, am21, 0, 0, 0); \
      av21 = __builtin_amdgcn_mfma_f32_16x16x32_bf16(ag2_, bv1##CUR, av21, 0, 0, 0); \
      am30 = __builtin_amdgcn_mfma_f32_16x16x32_bf16(af3_, bm0##CUR, am30, 0, 0, 0); \
      av30 = __builtin_amdgcn_mfma_f32_16x16x32_bf16(ag3_, bv0##CUR, av30, 0, 0, 0); \
      am31 = __builtin_amdgcn_mfma_f32_16x16x32_bf16(af3_, bm1##CUR, am31, 0, 0, 0); \
      av31 = __builtin_amdgcn_mfma_f32_16x16x32_bf16(ag3_, bv1##CUR, av31, 0, 0, 0); \
    } \
    if (!(LAST)) writeA(((S_) & 1) ^ 1); \
    __syncthreads(); \
  } while (0)

  // prologue: stage step 0 (A tile + B regs)
  loadX(0);
  writeA(0);
  LOADB(P, 0);
  __syncthreads();

  for (int s = 0; s < 24; s += 2) {
    KSTEP(s, P, Q, false);
    KSTEP(s + 1, Q, P, false);
  }
  KSTEP(24, P, Q, true);
#undef KSTEP
#undef LOADB

  // epilogue: eps1 + relu -> h (bf16) in global ws
  half8 eA0, eA1, eA2, eA3;
  if constexpr (UE) {
    const int4* esrc = ei4 + (size_t)bid * 1024 + tid;
    eA0 = *reinterpret_cast<const half8*>(&esrc[0]);
    eA1 = *reinterpret_cast<const half8*>(&esrc[256]);
    eA2 = *reinterpret_cast<const half8*>(&esrc[512]);
    eA3 = *reinterpret_cast<const half8*>(&esrc[768]);
  }
  const float INV = 0.031622776601683794f;  // 1/sqrt(1000)
#define EPIG(AM, AV, G, I, J) do { \
    const int rl_ = I * 16 + lhal * 4 + (G); \
    const int c_ = bc0 + wn * 32 + J * 16 + l15; \
    float mean_ = 0.5f * (AM)[G]; \
    float sd_ = 0.5f * sqrtf((AV)[G]); \
    float eps_; \
    if constexpr (UE) eps_ = (float)(eA##I[(J) * 4 + (G)]); \
    else eps_ = eps_part(k1a, k1b, (uint32_t)(gr0 + rl_) * 256u + (uint32_t)c_); \
    float h_ = fmaxf(mean_ + sd_ * (eps_ * INV), 0.0f); \
    hws[(size_t)(gr0 + rl_) * 256 + c_] = cvt_bf16(h_); \
  } while (0)
#define EPI(i, j) do { \
    EPIG(am##i##j, av##i##j, 0, i, j); \
    EPIG(am##i##j, av##i##j, 1, i, j); \
    EPIG(am##i##j, av##i##j, 2, i, j); \
    EPIG(am##i##j, av##i##j, 3, i, j); \
  } while (0)
  EPI(0, 0); EPI(0, 1); EPI(1, 0); EPI(1, 1);
  EPI(2, 0); EPI(2, 1); EPI(3, 0); EPI(3, 1);
#undef EPI
#undef EPIG
}

// ---- layer 2 on MFMA (r9 exact): BM2=128 rows/block, K=256 ----
__global__ __launch_bounds__(256, 4) void layer2(
    const u16* __restrict__ hws, const u16* __restrict__ w2p,
    float* __restrict__ out, uint32_t k2a, uint32_t k2b) {
  __shared__ u16 sH[2][BM2 * 32];  // [h, h^2][swizzled row*32+k] 16KB

  const int tid = threadIdx.x;
  const int lane = tid & 63;
  const int l15 = lane & 15;
  const int lhal = lane >> 4;  // 0..3
  const int wv = tid >> 6;     // wave 0..3 -> rows wv*32..wv*32+31
  const int gr0 = blockIdx.x * BM2;

  // staging: thread -> row = tid>>1, 16-u16 half = tid&1
  const int srow = tid >> 1;
  const int sq = (tid & 1) * 16;
  const u16* hrow = hws + (size_t)(gr0 + srow) * 256 + sq;
  const int sidx0 = (srow * 32 + sq) ^ ((srow & 7) << 3);
  const int sidx1 = (srow * 32 + sq + 8) ^ ((srow & 7) << 3);

  // B offsets (u16): col = l15, kgroup = lhal
  const uint32_t boff = (uint32_t)l15 * 256 + (uint32_t)lhal * 8;

  // A fragment LDS indices: rows wv*32 + i*16 + l15
#define AIDX2(i) ((((wv * 32 + i * 16 + l15) * 32 + lhal * 8)) ^ (((wv * 32 + i * 16 + l15) & 7) << 3))
  const int aidx0 = AIDX2(0);
  const int aidx1 = AIDX2(1);
#undef AIDX2

  floatx4 am0 = {0.f, 0.f, 0.f, 0.f}, am1 = {0.f, 0.f, 0.f, 0.f};
  floatx4 av0 = {0.f, 0.f, 0.f, 0.f}, av1 = {0.f, 0.f, 0.f, 0.f};

  for (int s = 0; s < 8; ++s) {
    __syncthreads();  // prev-step readers done before overwrite
    const short8 c0 = *reinterpret_cast<const short8*>(&hrow[s * 32]);
    const short8 c1 = *reinterpret_cast<const short8*>(&hrow[s * 32 + 8]);
    short8 s0, s1;
#define SQE(D, S, E) { const float f_ = bf2f((u16)(S)[E]); (D)[E] = (short)cvt_bf16(f_ * f_); }
    SQE(s0, c0, 0) SQE(s0, c0, 1) SQE(s0, c0, 2) SQE(s0, c0, 3)
    SQE(s0, c0, 4) SQE(s0, c0, 5) SQE(s0, c0, 6) SQE(s0, c0, 7)
    SQE(s1, c1, 0) SQE(s1, c1, 1) SQE(s1, c1, 2) SQE(s1, c1, 3)
    SQE(s1, c1, 4) SQE(s1, c1, 5) SQE(s1, c1, 6) SQE(s1, c1, 7)
#undef SQE
    *reinterpret_cast<short8*>(&sH[0][sidx0]) = c0;
    *reinterpret_cast<short8*>(&sH[0][sidx1]) = c1;
    *reinterpret_cast<short8*>(&sH[1][sidx0]) = s0;
    *reinterpret_cast<short8*>(&sH[1][sidx1]) = s1;
    __syncthreads();

    const short8 bm = *reinterpret_cast<const short8*>(&w2p[boff + s * 32]);
    const short8 bv = *reinterpret_cast<const short8*>(&w2p[W2SQ + boff + s * 32]);
    const short8 af0 = *reinterpret_cast<const short8*>(&sH[0][aidx0]);
    const short8 af1 = *reinterpret_cast<const short8*>(&sH[0][aidx1]);
    const short8 ag0 = *reinterpret_cast<const short8*>(&sH[1][aidx0]);
    const short8 ag1 = *reinterpret_cast<const short8*>(&sH[1][aidx1]);
    am0 = __builtin_amdgcn_mfma_f32_16x16x32_bf16(af0, bm, am0, 0, 0, 0);
    av0 = __builtin_amdgcn_mfma_f32_16x16x32_bf16(ag0, bv, av0, 0, 0, 0);
    am1 = __builtin_amdgcn_mfma_f32_16x16x32_bf16(af1, bm, am1, 0, 0, 0);
    av1 = __builtin_amdgcn_mfma_f32_16x16x32_bf16(ag1, bv, av1, 0, 0, 0);
  }

  // epilogue: C/D layout col=l15, row=(lane>>4)*4+g; only cols 0..9 exist
  const float INV = 0.031622776601683794f;
  if (l15 < N_OUT) {
#define L2E(I, G) do { \
    const int row_ = gr0 + wv * 32 + I * 16 + lhal * 4 + (G); \
    float mean_ = 0.5f * am##I[G]; \
    float sd_ = 0.5f * sqrtf(av##I[G]); \
    float eps_ = eps_part(k2a, k2b, (uint32_t)row_ * 10u + (uint32_t)l15); \
    out[(size_t)row_ * 10 + l15] = mean_ + sd_ * (eps_ * INV); \
  } while (0)
    L2E(0, 0); L2E(0, 1); L2E(0, 2); L2E(0, 3);
    L2E(1, 0); L2E(1, 1); L2E(1, 2); L2E(1, 3);
#undef L2E
  }
}

extern "C" void kernel_launch(void* const* d_in, const int* in_sizes, int n_in,
                              void* d_out, int out_size, void* d_ws, size_t ws_size,
                              hipStream_t stream) {
  const float* x = (const float*)d_in[0];
  const float* W1 = (const float*)d_in[1];
  const float* W2 = (const float*)d_in[2];
  float* outp = (float*)d_out;
  u16* bp = (u16*)d_ws;                           // 819200 B
  u16* w2p = (u16*)((char*)d_ws + W2_OFF);        // 16 KB

  // k1, k2 = jax.random.split(jax.random.key(42)), partitionable threefry
  uint32_t k1a, k1b, k2a, k2b;
  threefry2x32(0u, 42u, 0u, 0u, k1a, k1b);
  threefry2x32(0u, 42u, 0u, 1u, k2a, k2b);

  pack_w1<<<256, 256, 0, stream>>>(W1, bp);
  pack_w2<<<1, 256, 0, stream>>>(W2, w2p);

  const size_t need = (size_t)H_BIG + 33554432ull;  // h after eps: ~65 MB
  if (ws_size >= need) {
    int4* ei4 = (int4*)((char*)d_ws + EPS_OFF);
    u16* hws = (u16*)((char*)d_ws + H_BIG);
    rng1<<<2048, 256, 0, stream>>>(ei4, k1a, k1b);
    gemm1<1><<<2048, 256, 0, stream>>>(x, bp, hws, ei4, k1a, k1b);
    layer2<<<65536 / BM2, 256, 0, stream>>>(hws, w2p, outp, k2a, k2b);
  } else {
    u16* hws = (u16*)((char*)d_ws + H_SMALL);
    gemm1<0><<<2048, 256, 0, stream>>>(x, bp, hws, nullptr, k1a, k1b);
    layer2<<<65536 / BM2, 256, 0, stream>>>(hws, w2p, outp, k2a, k2b);
  }
}

// Round 17
// 194.361 us; speedup vs baseline: 1.2778x; 1.0674x over previous
//
#include <hip/hip_runtime.h>
#include <cstdint>

// Net_79139067396690: MC-dropout moment-propagation MLP.
//   h   = relu(0.5*x@W1^T + 0.5*sqrt((x^2)@(W1^2)^T) * eps1/sqrt(1000))
//   out =      0.5*h@W2^T + 0.5*sqrt((h^2)@(W2^2)^T) * eps2/sqrt(1000)
// Round 17: r16's RNG-hoist regressed (serial rng1 > hidden inline RNG);
// reverted. This round: OCCUPANCY. r9 wave tile 64x32 -> 128 acc regs ->
// ~190 live -> 12.8 waves/CU (40%). Shrink wave tile to 64x16 (32 acc regs,
// ~100 live) -> ~16-20 waves/CU. Block still 64 rows x 256 thr; block covers
// 64 cols (each wave = one 16-col strip); grid 1024x4 = 4096. Staging,
// swizzle, LDS, layer2, packs = r9 byte-identical. All reg state NAMED (#20).

#define K_DIM 784
#define KP 800                 // K padded to multiple of 32 in the W1 pack
#define N_HID 256
#define N_OUT 10
#define NSTEP 25               // KP/32
#define WSQ_OFF (N_HID * KP)   // u16 offset of squared-W1 pack
#define W2_OFF (832 * 1024)    // byte offset of W2 pack in d_ws
#define W2SQ 4096              // u16 offset of squared-W2 pack
#define H_OFF (1 << 20)        // byte offset of h in d_ws
#define BM2 128                // layer2 rows per block

using short8 = __attribute__((ext_vector_type(8))) short;
using floatx4 = __attribute__((ext_vector_type(4))) float;
typedef uint16_t u16;

// ---- Threefry-2x32 (JAX-compatible) ----
__host__ __device__ inline void threefry2x32(uint32_t k0, uint32_t k1,
                                             uint32_t x0, uint32_t x1,
                                             uint32_t& o0, uint32_t& o1) {
  uint32_t ks0 = k0, ks1 = k1, ks2 = k0 ^ k1 ^ 0x1BD11BDAu;
  x0 += ks0;
  x1 += ks1;
#define TFR(r) { x0 += x1; x1 = (x1 << (r)) | (x1 >> (32 - (r))); x1 ^= x0; }
  TFR(13) TFR(15) TFR(26) TFR(6)   x0 += ks1; x1 += ks2 + 1u;
  TFR(17) TFR(29) TFR(16) TFR(24)  x0 += ks2; x1 += ks0 + 2u;
  TFR(13) TFR(15) TFR(26) TFR(6)   x0 += ks0; x1 += ks1 + 3u;
  TFR(17) TFR(29) TFR(16) TFR(24)  x0 += ks1; x1 += ks2 + 4u;
  TFR(13) TFR(15) TFR(26) TFR(6)   x0 += ks2; x1 += ks0 + 5u;
#undef TFR
  o0 = x0;
  o1 = x1;
}

// bits -> N(0,1) ~= jax.random.normal (mantissa-uniform + Giles erfinv).
__device__ __forceinline__ float bits_to_normal(uint32_t bits) {
  const float lo = -0.99999994f;  // nextafterf(-1,0)
  float u01 = __uint_as_float((bits >> 9) | 0x3F800000u) - 1.0f;
  float u = fmaxf(lo, u01 * 2.0f + lo);
  float w = -__logf((1.0f - u) * (1.0f + u));
  float p;
  if (w < 5.0f) {
    w -= 2.5f;
    p = 2.81022636e-08f;
    p = fmaf(p, w, 3.43273939e-07f);
    p = fmaf(p, w, -3.5233877e-06f);
    p = fmaf(p, w, -4.39150654e-06f);
    p = fmaf(p, w, 0.00021858087f);
    p = fmaf(p, w, -0.00125372503f);
    p = fmaf(p, w, -0.00417768164f);
    p = fmaf(p, w, 0.246640727f);
    p = fmaf(p, w, 1.50140941f);
  } else {
    w = sqrtf(w) - 3.0f;
    p = -0.000200214257f;
    p = fmaf(p, w, 0.000100950558f);
    p = fmaf(p, w, 0.00134934322f);
    p = fmaf(p, w, -0.00367342844f);
    p = fmaf(p, w, 0.00573950773f);
    p = fmaf(p, w, -0.0076224613f);
    p = fmaf(p, w, 0.00943887047f);
    p = fmaf(p, w, 1.00167406f);
    p = fmaf(p, w, 2.83297682f);
  }
  return 1.41421356f * (p * u);
}

__device__ __forceinline__ float eps_part(uint32_t ka, uint32_t kb, uint32_t i) {
  uint32_t o0, o1;
  threefry2x32(ka, kb, 0u, i, o0, o1);
  return bits_to_normal(o0 ^ o1);
}

// f32 -> bf16 bits, round-to-nearest-even
__device__ __forceinline__ u16 cvt_bf16(float f) {
  uint32_t x = __float_as_uint(f);
  return (u16)((x + 0x7FFFu + ((x >> 16) & 1u)) >> 16);
}

__device__ __forceinline__ float bf2f(u16 b) {
  return __uint_as_float((uint32_t)b << 16);
}

// ---- pre-pack W1 -> bf16 {w, w^2}, K padded to 800 with zeros ----
__global__ __launch_bounds__(256) void pack_w1(const float* __restrict__ W1,
                                               u16* __restrict__ bp) {
  const int col = blockIdx.x;  // 0..255
  for (int k = threadIdx.x; k < KP; k += 256) {
    float w = (k < K_DIM) ? W1[col * K_DIM + k] : 0.0f;
    bp[col * KP + k] = cvt_bf16(w);
    bp[WSQ_OFF + col * KP + k] = cvt_bf16(w * w);
  }
}

// ---- pre-pack W2 -> bf16 {w, w^2}, cols padded 10->16 with zeros ----
__global__ __launch_bounds__(256) void pack_w2(const float* __restrict__ W2,
                                               u16* __restrict__ w2p) {
#pragma unroll
  for (int i = 0; i < 16; ++i) {
    int g = threadIdx.x + i * 256;  // 4096 = 16*256
    int col = g >> 8, k = g & 255;
    float w = (col < N_OUT) ? W2[col * N_HID + k] : 0.0f;
    w2p[g] = cvt_bf16(w);
    w2p[W2SQ + g] = cvt_bf16(w * w);
  }
}

// ---- GEMM1 + eps1 + relu -> h (bf16, global) ----
// Block: 256 thr = 4 waves; 64 rows x 64 cols; wave = 64 x 16 (32 acc regs).
// Grid: 1024 row-tiles x 4 col-tiles = 4096 blocks.
__global__ __launch_bounds__(256, 4) void gemm1(
    const float* __restrict__ x, const u16* __restrict__ bp,
    u16* __restrict__ hws, uint32_t k1a, uint32_t k1b) {
  __shared__ u16 sA[2][2][64 * 32];  // [dbuf][x, x^2][swizzled row*32+k] 16KB

  const int tid = threadIdx.x;
  const int lane = tid & 63;
  const int l15 = lane & 15;
  const int lhal = lane >> 4;      // 0..3
  const int wn = tid >> 6;         // wave id 0..3 -> 16-col strip
  const int bid = blockIdx.x;
  const int gr0 = (bid >> 2) * 64;        // row origin
  const int bc0 = (bid & 3) * 64;         // col origin

  // staging: thread -> (row 0..63, 8-wide k chunk)  [r9 exact]
  const int srow = tid >> 2;
  const int skq = (tid & 3) * 8;
  const float* xptr = x + (size_t)(gr0 + srow) * K_DIM + skq;
  const int sidx = (srow * 32 + skq) ^ ((srow & 7) << 3);

  // B offset (u16 units) for this wave's single 16-col fragment
  const uint32_t boff0 = (uint32_t)(bc0 + wn * 16 + l15) * KP + (uint32_t)lhal * 8;

  // A fragment LDS indices (rows i*16 + l15, k-group lhal*8), NAMED [r9 exact]
#define AIDX(i) ((((i * 16 + l15) * 32 + lhal * 8)) ^ (((i * 16 + l15) & 7) << 3))
  const int aidx0 = AIDX(0);
  const int aidx1 = AIDX(1);
  const int aidx2 = AIDX(2);
  const int aidx3 = AIDX(3);
#undef AIDX

  // NAMED accumulators: am{i}, av{i}, i=0..3 (8 floatx4 = 32 regs)
  floatx4 am0 = {0.f, 0.f, 0.f, 0.f}, av0 = {0.f, 0.f, 0.f, 0.f};
  floatx4 am1 = {0.f, 0.f, 0.f, 0.f}, av1 = {0.f, 0.f, 0.f, 0.f};
  floatx4 am2 = {0.f, 0.f, 0.f, 0.f}, av2 = {0.f, 0.f, 0.f, 0.f};
  floatx4 am3 = {0.f, 0.f, 0.f, 0.f}, av3 = {0.f, 0.f, 0.f, 0.f};

  // NAMED ping/pong B register sets (8 VGPR each)
  short8 bmP, bvP, bmQ, bvQ;
#define LOADB(S, KK) do { \
    const u16* bpk_ = bp + (KK); \
    bm##S = *reinterpret_cast<const short8*>(&bpk_[boff0]); \
    bv##S = *reinterpret_cast<const short8*>(&bpk_[WSQ_OFF + boff0]); \
  } while (0)

  float4 q0, q1;
  auto loadX = [&](int kk) {
    if (kk + skq + 8 <= K_DIM) {  // K tail (784 = 24*32+16): zero-fill OOB
      q0 = *reinterpret_cast<const float4*>(xptr + kk);
      q1 = *reinterpret_cast<const float4*>(xptr + kk + 4);
    } else {
      q0 = make_float4(0.f, 0.f, 0.f, 0.f);
      q1 = make_float4(0.f, 0.f, 0.f, 0.f);
    }
  };
  auto writeA = [&](int buf) {
    short8 va, v2;
    va[0] = (short)cvt_bf16(q0.x); v2[0] = (short)cvt_bf16(q0.x * q0.x);
    va[1] = (short)cvt_bf16(q0.y); v2[1] = (short)cvt_bf16(q0.y * q0.y);
    va[2] = (short)cvt_bf16(q0.z); v2[2] = (short)cvt_bf16(q0.z * q0.z);
    va[3] = (short)cvt_bf16(q0.w); v2[3] = (short)cvt_bf16(q0.w * q0.w);
    va[4] = (short)cvt_bf16(q1.x); v2[4] = (short)cvt_bf16(q1.x * q1.x);
    va[5] = (short)cvt_bf16(q1.y); v2[5] = (short)cvt_bf16(q1.y * q1.y);
    va[6] = (short)cvt_bf16(q1.z); v2[6] = (short)cvt_bf16(q1.z * q1.z);
    va[7] = (short)cvt_bf16(q1.w); v2[7] = (short)cvt_bf16(q1.w * q1.w);
    *reinterpret_cast<short8*>(&sA[buf][0][sidx]) = va;
    *reinterpret_cast<short8*>(&sA[buf][1][sidx]) = v2;
  };

  // One K-step: uses B set CUR (already resident), prefetches set NXT.
#define KSTEP(S_, CUR, NXT, LAST) do { \
    const int kk_ = (S_) * 32; \
    if (!(LAST)) { loadX(kk_ + 32); LOADB(NXT, kk_ + 32); } \
    const u16* sc0_ = &sA[(S_) & 1][0][0]; \
    const u16* sc1_ = &sA[(S_) & 1][1][0]; \
    { \
      const short8 af0_ = *reinterpret_cast<const short8*>(&sc0_[aidx0]); \
      const short8 ag0_ = *reinterpret_cast<const short8*>(&sc1_[aidx0]); \
      const short8 af1_ = *reinterpret_cast<const short8*>(&sc0_[aidx1]); \
      const short8 ag1_ = *reinterpret_cast<const short8*>(&sc1_[aidx1]); \
      const short8 af2_ = *reinterpret_cast<const short8*>(&sc0_[aidx2]); \
      const short8 ag2_ = *reinterpret_cast<const short8*>(&sc1_[aidx2]); \
      const short8 af3_ = *reinterpret_cast<const short8*>(&sc0_[aidx3]); \
      const short8 ag3_ = *reinterpret_cast<const short8*>(&sc1_[aidx3]); \
      am0 = __builtin_amdgcn_mfma_f32_16x16x32_bf16(af0_, bm##CUR, am0, 0, 0, 0); \
      av0 = __builtin_amdgcn_mfma_f32_16x16x32_bf16(ag0_, bv##CUR, av0, 0, 0, 0); \
      am1 = __builtin_amdgcn_mfma_f32_16x16x32_bf16(af1_, bm##CUR, am1, 0, 0, 0); \
      av1 = __builtin_amdgcn_mfma_f32_16x16x32_bf16(ag1_, bv##CUR, av1, 0, 0, 0); \
      am2 = __builtin_amdgcn_mfma_f32_16x16x32_bf16(af2_, bm##CUR, am2, 0, 0, 0); \
      av2 = __builtin_amdgcn_mfma_f32_16x16x32_bf16(ag2_, bv##CUR, av2, 0, 0, 0); \
      am3 = __builtin_amdgcn_mfma_f32_16x16x32_bf16(af3_, bm##CUR, am3, 0, 0, 0); \
      av3 = __builtin_amdgcn_mfma_f32_16x16x32_bf16(ag3_, bv##CUR, av3, 0, 0, 0); \
    } \
    if (!(LAST)) writeA(((S_) & 1) ^ 1); \
    __syncthreads(); \
  } while (0)

  // prologue: stage step 0 (A tile + B regs)
  loadX(0);
  writeA(0);
  LOADB(P, 0);
  __syncthreads();

  for (int s = 0; s < 24; s += 2) {
    KSTEP(s, P, Q, false);
    KSTEP(s + 1, Q, P, false);
  }
  KSTEP(24, P, Q, true);
#undef KSTEP
#undef LOADB

  // epilogue: eps1 + relu -> h (bf16) in global ws (16 draws/thread)
  const float INV = 0.031622776601683794f;  // 1/sqrt(1000)
  const int ccol = bc0 + wn * 16 + l15;
#define EPIG(AM, AV, G, I) do { \
    const int rl_ = I * 16 + lhal * 4 + (G); \
    float mean_ = 0.5f * (AM)[G]; \
    float sd_ = 0.5f * sqrtf((AV)[G]); \
    uint32_t idx_ = (uint32_t)(gr0 + rl_) * 256u + (uint32_t)ccol; \
    float eps_ = eps_part(k1a, k1b, idx_); \
    float h_ = fmaxf(mean_ + sd_ * (eps_ * INV), 0.0f); \
    hws[(size_t)(gr0 + rl_) * 256 + ccol] = cvt_bf16(h_); \
  } while (0)
#define EPI(i) do { \
    EPIG(am##i, av##i, 0, i); \
    EPIG(am##i, av##i, 1, i); \
    EPIG(am##i, av##i, 2, i); \
    EPIG(am##i, av##i, 3, i); \
  } while (0)
  EPI(0); EPI(1); EPI(2); EPI(3);
#undef EPI
#undef EPIG
}

// ---- layer 2 on MFMA (r9 exact): BM2=128 rows/block, K=256 ----
__global__ __launch_bounds__(256, 4) void layer2(
    const u16* __restrict__ hws, const u16* __restrict__ w2p,
    float* __restrict__ out, uint32_t k2a, uint32_t k2b) {
  __shared__ u16 sH[2][BM2 * 32];  // [h, h^2][swizzled row*32+k] 16KB

  const int tid = threadIdx.x;
  const int lane = tid & 63;
  const int l15 = lane & 15;
  const int lhal = lane >> 4;  // 0..3
  const int wv = tid >> 6;     // wave 0..3 -> rows wv*32..wv*32+31
  const int gr0 = blockIdx.x * BM2;

  // staging: thread -> row = tid>>1, 16-u16 half = tid&1
  const int srow = tid >> 1;
  const int sq = (tid & 1) * 16;
  const u16* hrow = hws + (size_t)(gr0 + srow) * 256 + sq;
  const int sidx0 = (srow * 32 + sq) ^ ((srow & 7) << 3);
  const int sidx1 = (srow * 32 + sq + 8) ^ ((srow & 7) << 3);

  // B offsets (u16): col = l15, kgroup = lhal
  const uint32_t boff = (uint32_t)l15 * 256 + (uint32_t)lhal * 8;

  // A fragment LDS indices: rows wv*32 + i*16 + l15
#define AIDX2(i) ((((wv * 32 + i * 16 + l15) * 32 + lhal * 8)) ^ (((wv * 32 + i * 16 + l15) & 7) << 3))
  const int aidx0 = AIDX2(0);
  const int aidx1 = AIDX2(1);
#undef AIDX2

  floatx4 am0 = {0.f, 0.f, 0.f, 0.f}, am1 = {0.f, 0.f, 0.f, 0.f};
  floatx4 av0 = {0.f, 0.f, 0.f, 0.f}, av1 = {0.f, 0.f, 0.f, 0.f};

  for (int s = 0; s < 8; ++s) {
    __syncthreads();  // prev-step readers done before overwrite
    const short8 c0 = *reinterpret_cast<const short8*>(&hrow[s * 32]);
    const short8 c1 = *reinterpret_cast<const short8*>(&hrow[s * 32 + 8]);
    short8 s0, s1;
#define SQE(D, S, E) { const float f_ = bf2f((u16)(S)[E]); (D)[E] = (short)cvt_bf16(f_ * f_); }
    SQE(s0, c0, 0) SQE(s0, c0, 1) SQE(s0, c0, 2) SQE(s0, c0, 3)
    SQE(s0, c0, 4) SQE(s0, c0, 5) SQE(s0, c0, 6) SQE(s0, c0, 7)
    SQE(s1, c1, 0) SQE(s1, c1, 1) SQE(s1, c1, 2) SQE(s1, c1, 3)
    SQE(s1, c1, 4) SQE(s1, c1, 5) SQE(s1, c1, 6) SQE(s1, c1, 7)
#undef SQE
    *reinterpret_cast<short8*>(&sH[0][sidx0]) = c0;
    *reinterpret_cast<short8*>(&sH[0][sidx1]) = c1;
    *reinterpret_cast<short8*>(&sH[1][sidx0]) = s0;
    *reinterpret_cast<short8*>(&sH[1][sidx1]) = s1;
    __syncthreads();

    const short8 bm = *reinterpret_cast<const short8*>(&w2p[boff + s * 32]);
    const short8 bv = *reinterpret_cast<const short8*>(&w2p[W2SQ + boff + s * 32]);
    const short8 af0 = *reinterpret_cast<const short8*>(&sH[0][aidx0]);
    const short8 af1 = *reinterpret_cast<const short8*>(&sH[0][aidx1]);
    const short8 ag0 = *reinterpret_cast<const short8*>(&sH[1][aidx0]);
    const short8 ag1 = *reinterpret_cast<const short8*>(&sH[1][aidx1]);
    am0 = __builtin_amdgcn_mfma_f32_16x16x32_bf16(af0, bm, am0, 0, 0, 0);
    av0 = __builtin_amdgcn_mfma_f32_16x16x32_bf16(ag0, bv, av0, 0, 0, 0);
    am1 = __builtin_amdgcn_mfma_f32_16x16x32_bf16(af1, bm, am1, 0, 0, 0);
    av1 = __builtin_amdgcn_mfma_f32_16x16x32_bf16(ag1, bv, av1, 0, 0, 0);
  }

  // epilogue: C/D layout col=l15, row=(lane>>4)*4+g; only cols 0..9 exist
  const float INV = 0.031622776601683794f;
  if (l15 < N_OUT) {
#define L2E(I, G) do { \
    const int row_ = gr0 + wv * 32 + I * 16 + lhal * 4 + (G); \
    float mean_ = 0.5f * am##I[G]; \
    float sd_ = 0.5f * sqrtf(av##I[G]); \
    float eps_ = eps_part(k2a, k2b, (uint32_t)row_ * 10u + (uint32_t)l15); \
    out[(size_t)row_ * 10 + l15] = mean_ + sd_ * (eps_ * INV); \
  } while (0)
    L2E(0, 0); L2E(0, 1); L2E(0, 2); L2E(0, 3);
    L2E(1, 0); L2E(1, 1); L2E(1, 2); L2E(1, 3);
#undef L2E
  }
}

extern "C" void kernel_launch(void* const* d_in, const int* in_sizes, int n_in,
                              void* d_out, int out_size, void* d_ws, size_t ws_size,
                              hipStream_t stream) {
  const float* x = (const float*)d_in[0];
  const float* W1 = (const float*)d_in[1];
  const float* W2 = (const float*)d_in[2];
  float* outp = (float*)d_out;
  u16* bp = (u16*)d_ws;                           // 819200 B
  u16* w2p = (u16*)((char*)d_ws + W2_OFF);        // 16 KB
  u16* hws = (u16*)((char*)d_ws + H_OFF);         // 33.5 MB

  // k1, k2 = jax.random.split(jax.random.key(42)), partitionable threefry
  uint32_t k1a, k1b, k2a, k2b;
  threefry2x32(0u, 42u, 0u, 0u, k1a, k1b);
  threefry2x32(0u, 42u, 0u, 1u, k2a, k2b);

  pack_w1<<<256, 256, 0, stream>>>(W1, bp);
  pack_w2<<<1, 256, 0, stream>>>(W2, w2p);
  gemm1<<<4096, 256, 0, stream>>>(x, bp, hws, k1a, k1b);
  layer2<<<65536 / BM2, 256, 0, stream>>>(hws, w2p, outp, k2a, k2b);
}